// Round 11
// baseline (337.941 us; speedup 1.0000x reference)
//
#include <hip/hip_runtime.h>
#include <cstdint>

#define B_    128
#define T_    2048
#define NIN_  16
#define NH_   128
#define NOUT_ 5

#define ALPHA_I_ 0.75f
#define ALPHA_V_ 0.96875f
#define THETA_   64.0f

#define NCHUNK_ 16
#define CHT_    128     // data timesteps per chunk
#define WARM_   96      // warmup timesteps (3 sub-chunks of 32)

typedef short bf16x8 __attribute__((ext_vector_type(8)));
typedef float f32x16 __attribute__((ext_vector_type(16)));

__device__ __forceinline__ float mulrn(float a, float b) { return __fmul_rn(a, b); }
__device__ __forceinline__ float addrn(float a, float b) { return __fadd_rn(a, b); }

__device__ __forceinline__ uint16_t f2bf(float x) {  // RNE f32->bf16
  uint32_t u = __float_as_uint(x);
  return (uint16_t)((u + 0x7FFFu + ((u >> 16) & 1u)) >> 16);
}

// nibble LUT (16 x uint2 in LDS, bank-conflict-free): bit j -> bf16 1.0/0.0
__device__ __forceinline__ bf16x8 expand8(const uint2* __restrict__ lut, uint32_t byt) {
  uint2 lo = lut[byt & 15u];
  uint2 h  = lut[byt >> 4];
  union { uint32_t w[4]; bf16x8 f; } r;
  r.w[0] = lo.x; r.w[1] = lo.y; r.w[2] = h.x; r.w[3] = h.y;
  return r.f;
}

__device__ __forceinline__ void lut_init(uint2* s_lut, int tid) {
  if (tid < 16) {
    uint32_t w0 = ((tid & 1) ? 0x3F80u : 0u) | ((tid & 2) ? 0x3F800000u : 0u);
    uint32_t w1 = ((tid & 4) ? 0x3F80u : 0u) | ((tid & 8) ? 0x3F800000u : 0u);
    s_lut[tid] = make_uint2(w0, w1);
  }
}

// ---------------------------------------------------------------------------
// prep (1024 threads): weight_norm (x64 folded). w1swz / wswz in the
// R5-R10-verified MFMA B-fragment swizzle. w3T[c][0..4]=w3, [5]=f2,[6]=1-f2.
// efo: e=floor(d)+1 (includes delay_shift1's +1). Zero counts.
// ---------------------------------------------------------------------------
__global__ __launch_bounds__(1024) void prep_kernel(
    const float* __restrict__ fc1_v, const float* __restrict__ fc1_g,
    const float* __restrict__ fc2_v, const float* __restrict__ fc2_g,
    const float* __restrict__ fc3_v, const float* __restrict__ fc3_g,
    const float* __restrict__ delay1, const float* __restrict__ delay2,
    uint16_t* __restrict__ w1swz, uint16_t* __restrict__ wswz,
    float* __restrict__ w3T, float4* __restrict__ efo1, float4* __restrict__ efo2,
    float* __restrict__ counts) {
  __shared__ float s_g2[NH_], s_n2[NH_];
  int tid = threadIdx.x;
  if (tid < NH_) {
    {
      float ss = 0.f;
      for (int c = 0; c < NH_; c++) { float vv = fc2_v[tid * NH_ + c]; ss = __fmaf_rn(vv, vv, ss); }
      s_n2[tid] = sqrtf(ss);
      s_g2[tid] = fc2_g[tid];
    }
    {
      float ss = 0.f;
      for (int c = 0; c < NIN_; c++) { float vv = fc1_v[tid * NIN_ + c]; ss = __fmaf_rn(vv, vv, ss); }
      float nrm = sqrtf(ss);
      float g = fc1_g[tid];
      int mt = tid >> 5;
      for (int c = 0; c < NIN_; c++) {
        float wv = 64.0f * __fdiv_rn(mulrn(g, fc1_v[tid * NIN_ + c]), nrm);
        int lane = (tid & 31) + 32 * ((c >> 3) & 1);
        int j = c & 7;
        w1swz[(mt * 64 + lane) * 8 + j] = f2bf(wv);
      }
    }
    {
      float d1 = delay1[tid];
      float fl = floorf(d1);
      float f = __fsub_rn(d1, fl);
      efo1[tid] = make_float4(__int_as_float((int)fl + 1), f, __fsub_rn(1.0f, f), 0.f);
      float d2 = delay2[tid];
      float fl2 = floorf(d2);
      float f2v = __fsub_rn(d2, fl2);
      efo2[tid] = make_float4(__int_as_float((int)fl2 + 1), f2v, __fsub_rn(1.0f, f2v), 0.f);
      w3T[tid * 8 + 5] = f2v;
      w3T[tid * 8 + 6] = __fsub_rn(1.0f, f2v);
      w3T[tid * 8 + 7] = 0.f;
    }
  }
  if (tid < NOUT_) {
    float ss = 0.f;
    for (int c = 0; c < NH_; c++) { float vv = fc3_v[tid * NH_ + c]; ss = __fmaf_rn(vv, vv, ss); }
    float nrm = sqrtf(ss);
    float g = fc3_g[tid];
    for (int c = 0; c < NH_; c++)
      w3T[c * 8 + tid] = 64.0f * __fdiv_rn(mulrn(g, fc3_v[tid * NH_ + c]), nrm);
  }
  if (tid < 3) counts[tid] = 0.f;
  __syncthreads();
  for (int i = tid; i < NH_ * NH_; i += 1024) {
    int o = i >> 7, c = i & 127;
    float wv = 64.0f * __fdiv_rn(mulrn(s_g2[o], fc2_v[i]), s_n2[o]);
    float d1 = delay1[c];
    float f = __fsub_rn(d1, floorf(d1));
    int lane = (o & 31) + 32 * ((c >> 3) & 1);
    int ks = c >> 4, j = c & 7, mt = o >> 5;
    wswz[((size_t)((0 * 4 + mt) * 8 + ks) * 64 + lane) * 8 + j] = f2bf(__fmul_rn(wv, f));
    wswz[((size_t)((1 * 4 + mt) * 8 + ks) * 64 + lane) * 8 + j] =
        f2bf(__fmul_rn(wv, __fsub_rn(1.0f, f)));
  }
}

// ---------------------------------------------------------------------------
// pack: input f32 spikes (B,16,T) -> 16-bit channel masks Xb[b][t] via ballot.
// ---------------------------------------------------------------------------
__global__ __launch_bounds__(256) void pack_kernel(const float* __restrict__ spike,
                                                   uint16_t* __restrict__ Xb) {
  int gw = blockIdx.x * 4 + (threadIdx.x >> 6);
  int lane = threadIdx.x & 63;
  int b = gw >> 5;
  int t = (gw & 31) * 64 + lane;
  const float* sp = spike + (size_t)b * NIN_ * T_ + t;
  uint32_t mask = 0;
#pragma unroll
  for (int c = 0; c < NIN_; c++) {
    unsigned long long bal = __ballot(sp[(size_t)c * T_] != 0.f);
    mask |= (uint32_t)((bal >> lane) & 1ull) << c;
  }
  Xb[(size_t)b * T_ + t] = (uint16_t)mask;
}

// ---------------------------------------------------------------------------
// Gather a wave's 2-tile (tiles A,B; 64o x 32t) MFMA result so that every
// lane holds all 32 t for one o, via 16 batched shfl_xor(32) (NOT in the
// scan chain). D layout (R6-R10-verified): row t = (r&3)+8*(r>>2)+4*hi,
// col o = lane&31. Then scan 32 steps fully in-register; o = pair*64+lane.
// ---------------------------------------------------------------------------
#define GATHER_AND_SCAN(aA, aB, hi, u, v, m)                               \
  {                                                                        \
    float evenQ[16], oddQ[16];                                             \
    _Pragma("unroll") for (int r = 0; r < 16; r++) {                       \
      float tmp = hi ? aA[r] : aB[r];                                      \
      float rcv = __shfl_xor(tmp, 32, 64);                                 \
      evenQ[r] = hi ? rcv : aA[r];                                         \
      oddQ[r] = hi ? aB[r] : rcv;                                          \
    }                                                                      \
    m = 0u;                                                                \
    _Pragma("unroll") for (int t = 0; t < 32; t++) {                       \
      int q = t >> 2;                                                      \
      int base = 4 * (q >> 1) + (t & 3);                                   \
      float z = (q & 1) ? oddQ[base] : evenQ[base];                        \
      u = addrn(mulrn(ALPHA_I_, u), z);                                    \
      v = addrn(mulrn(ALPHA_V_, v), u);                                    \
      bool sbit = (v >= THETA_);                                           \
      v = sbit ? 0.f : v;                                                  \
      m |= sbit ? (1u << t) : 0u;                                          \
    }                                                                      \
  }

// ---------------------------------------------------------------------------
// Fused layer 1: wave = 2 o-tiles (shared A-frag from input bits, 2 MFMA),
// gather + in-register scan, coalesced bit store + counts. Waves independent.
// grid (NCHUNK_, B), block 128 (2 waves = o pairs {0-63},{64-127}).
// 4 waves/SIMD via launch bounds for latency hiding.
// ---------------------------------------------------------------------------
__global__ __launch_bounds__(128, 4) void fused_layer1(const uint16_t* __restrict__ Xb,
                                                       const uint16_t* __restrict__ w1swz,
                                                       uint32_t* __restrict__ sbits2,
                                                       float* __restrict__ cnt) {
  __shared__ uint2 s_lut[16];
  int tid = threadIdx.x;
  int pair = tid >> 6, lane = tid & 63;
  int hi = lane >> 5, tl = lane & 31;
  int ci = blockIdx.x, b = blockIdx.y;
  lut_init(s_lut, tid);
  const bf16x8* w1v = (const bf16x8*)w1swz;
  bf16x8 wA = w1v[(pair * 2 + 0) * 64 + lane];
  bf16x8 wB = w1v[(pair * 2 + 1) * 64 + lane];
  __syncthreads();

  int wch = (ci == 0) ? 0 : (WARM_ / 32);
  int nch = CHT_ / 32 + wch;
  int chbase0 = ci * CHT_ - wch * 32;
  const uint16_t* xb = Xb + (size_t)b * T_;
  uint32_t* sb = sbits2 + (size_t)b * 68 * NH_;

  float u = 0.f, v = 0.f, csum = 0.f;
  uint32_t x = xb[chbase0 + tl];
  for (int g = 0; g < nch; g++) {
    uint32_t xn = (g + 1 < nch) ? (uint32_t)xb[chbase0 + (g + 1) * 32 + tl] : 0u;
    uint32_t byt = (x >> (8 * hi)) & 0xFFu;
    bf16x8 e = expand8(s_lut, byt);
    f32x16 aA, aB;
#pragma unroll
    for (int r = 0; r < 16; r++) { aA[r] = 0.f; aB[r] = 0.f; }
    aA = __builtin_amdgcn_mfma_f32_32x32x16_bf16(e, wA, aA, 0, 0, 0);
    aB = __builtin_amdgcn_mfma_f32_32x32x16_bf16(e, wB, aB, 0, 0, 0);
    uint32_t m;
    GATHER_AND_SCAN(aA, aB, hi, u, v, m);
    if (g >= wch) {
      int gw = (chbase0 + g * 32) >> 5;
      sb[(2 + gw) * NH_ + pair * 64 + lane] = m;
      int pc = __popc(m);
      if (gw == 63) pc -= (int)(m >> 31);
      csum += (float)pc;
    }
    x = xn;
  }
  if (ci == 0) { sb[0 * NH_ + pair * 64 + lane] = 0u; sb[1 * NH_ + pair * 64 + lane] = 0u; }
  if (ci == NCHUNK_ - 1) { sb[66 * NH_ + pair * 64 + lane] = 0u; sb[67 * NH_ + pair * 64 + lane] = 0u; }
  for (int off = 32; off; off >>= 1) csum += __shfl_down(csum, off, 64);
  if (lane == 0) atomicAdd(cnt, csum);
}

// ---------------------------------------------------------------------------
// Fused layer 2: block = 8 waves of the SAME o-pair (pb), handling chunks
// bx*8 .. bx*8+7. Weight fragments staged ONCE into LDS (32 KB) shared by
// all 8 waves -> 2 blocks/CU = 16 waves/CU = 4 waves/SIMD (VGPR capped 128).
// Per ks: 4 ds_read_b128 weights + 2 LUT expands + 4 MFMA. Barrier-free loop.
// grid (NCHUNK_/8, 2, B), block 512.
// ---------------------------------------------------------------------------
__global__ __launch_bounds__(512, 4) void fused_layer2(const uint32_t* __restrict__ PTpad,
                                                       const uint16_t* __restrict__ wswz,
                                                       uint32_t* __restrict__ sbits2,
                                                       float* __restrict__ cnt) {
  __shared__ uint16_t s_w[4 * 8 * 64 * 8];  // [arr][ks][lane][j], 32 KB
  __shared__ uint2 s_lut[16];
  int tid = threadIdx.x;
  int wv = tid >> 6, lane = tid & 63;
  int hi = lane >> 5, tl = lane & 31;
  int pb = blockIdx.y, b = blockIdx.z;
  int ci = blockIdx.x * 8 + wv;
  lut_init(s_lut, tid);
  {
    // arr: 0=WfA 1=WofA 2=WfB 3=WofB  (A: mt=2pb, B: mt=2pb+1)
    const uint4* wsrc = (const uint4*)wswz;
    uint4* wdst = (uint4*)s_w;
    for (int i = tid; i < 2048; i += 512) {
      int arr = i >> 9, rest = i & 511;      // rest = ks*64 + lane
      int half = arr & 1, mt = 2 * pb + (arr >> 1);
      wdst[i] = wsrc[(size_t)((half * 4 + mt) * 8) * 64 + rest];
    }
  }
  __syncthreads();

  int wch = (ci == 0) ? 0 : (WARM_ / 32);
  int nch = CHT_ / 32 + wch;
  int chbase0 = ci * CHT_ - wch * 32;
  const uint4* pt = (const uint4*)PTpad + (size_t)b * (T_ + 1);
  uint32_t* sb = sbits2 + (size_t)b * 68 * NH_;
  const bf16x8* wlds = (const bf16x8*)s_w;

  float u = 0.f, v = 0.f, csum = 0.f;
  uint4 R0 = pt[chbase0 + tl];
  uint4 R1 = pt[chbase0 + tl + 1];
  for (int g = 0; g < nch; g++) {
    uint4 R0n = R0, R1n = R1;
    if (g + 1 < nch) {
      R0n = pt[chbase0 + (g + 1) * 32 + tl];
      R1n = pt[chbase0 + (g + 1) * 32 + tl + 1];
    }
    uint32_t r0w[4] = {R0.x, R0.y, R0.z, R0.w};
    uint32_t r1w[4] = {R1.x, R1.y, R1.z, R1.w};
    f32x16 aA, aB;
#pragma unroll
    for (int r = 0; r < 16; r++) { aA[r] = 0.f; aB[r] = 0.f; }
#pragma unroll
    for (int ks = 0; ks < 8; ks++) {
      int sh = 16 * (ks & 1) + 8 * hi;
      uint32_t b0 = (r0w[ks >> 1] >> sh) & 0xFFu;  // tap s[t-e-1] -> Wf
      uint32_t b1 = (r1w[ks >> 1] >> sh) & 0xFFu;  // tap s[t-e]   -> Wof
      bf16x8 e0 = expand8(s_lut, b0);
      bf16x8 e1 = expand8(s_lut, b1);
      bf16x8 wfA = wlds[0 * 512 + ks * 64 + lane];
      bf16x8 woA = wlds[1 * 512 + ks * 64 + lane];
      bf16x8 wfB = wlds[2 * 512 + ks * 64 + lane];
      bf16x8 woB = wlds[3 * 512 + ks * 64 + lane];
      aA = __builtin_amdgcn_mfma_f32_32x32x16_bf16(e0, wfA, aA, 0, 0, 0);
      aA = __builtin_amdgcn_mfma_f32_32x32x16_bf16(e1, woA, aA, 0, 0, 0);
      aB = __builtin_amdgcn_mfma_f32_32x32x16_bf16(e0, wfB, aB, 0, 0, 0);
      aB = __builtin_amdgcn_mfma_f32_32x32x16_bf16(e1, woB, aB, 0, 0, 0);
    }
    uint32_t m;
    GATHER_AND_SCAN(aA, aB, hi, u, v, m);
    if (g >= wch) {
      int gw = (chbase0 + g * 32) >> 5;
      sb[(2 + gw) * NH_ + pb * 64 + lane] = m;
      int pc = __popc(m);
      if (gw == 63) pc -= (int)(m >> 31);
      csum += (float)pc;
    }
    R0 = R0n; R1 = R1n;
  }
  if (ci == 0) { sb[0 * NH_ + pb * 64 + lane] = 0u; sb[1 * NH_ + pb * 64 + lane] = 0u; }
  if (ci == NCHUNK_ - 1) { sb[66 * NH_ + pb * 64 + lane] = 0u; sb[67 * NH_ + pb * 64 + lane] = 0u; }
  for (int off = 32; off; off >>= 1) csum += __shfl_down(csum, off, 64);
  if (lane == 0) atomicAdd(cnt, csum);
}

// ---------------------------------------------------------------------------
// bit transpose + delay pre-shift: grid (T/256, B); one t per thread.
// 10-word LDS window per channel; per-c funnel read as one unaligned 8B
// access (-> ds_read2_b32, halves LDS instruction count vs 2x b32).
// PTpad[b][1+t] bit c = s[c][t - e_c]; PTpad[b][0] = 0.
// ---------------------------------------------------------------------------
__global__ __launch_bounds__(256) void transpose_kernel(const uint32_t* __restrict__ sbits2,
                                                        const float4* __restrict__ efo,
                                                        uint32_t* __restrict__ PTpad) {
  __shared__ uint32_t rows[NH_][11];  // k=0..9 (+1 pad)
  int tid = threadIdx.x;
  int b = blockIdx.y;
  int t0blk = blockIdx.x * 256;
  int w0 = t0blk >> 5;
  const uint32_t* src = sbits2 + (size_t)b * 68 * NH_;
  for (int i = tid; i < NH_ * 10; i += 256) {
    int k = i >> 7, c = i & 127;
    rows[c][k] = src[(1 + w0 + k) * NH_ + c];  // slot 1+w0+k (guards at 0,1,66,67)
  }
  __syncthreads();

  int t = t0blk + tid;
  uint32_t wacc[4] = {0u, 0u, 0u, 0u};
#pragma unroll
  for (int c = 0; c < NH_; c++) {
    int e = __float_as_int(efo[c].x);           // uniform -> scalar load
    int bitpos = t - e;                          // >= t0blk-11
    int wi = (bitpos >> 5) - w0 + 1;             // in [0, 9]
    int sh = bitpos & 31;
    uint2 w2;
    __builtin_memcpy(&w2, &rows[c][wi], 8);      // unaligned 8B -> ds_read2_b32
    uint32_t bit = (uint32_t)(((((unsigned long long)w2.y << 32) | w2.x) >> sh)) & 1u;
    wacc[c >> 5] |= bit << (c & 31);
  }
  uint4* outp = (uint4*)PTpad + (size_t)b * (T_ + 1);
  outp[1 + t] = make_uint4(wacc[0], wacc[1], wacc[2], wacc[3]);
  if (t == 0) outp[0] = make_uint4(0u, 0u, 0u, 0u);
}

// ---------------------------------------------------------------------------
// gemm3 (vector): 5 outputs from pre-shifted PT rows.
// ---------------------------------------------------------------------------
__global__ __launch_bounds__(256) void gemm3_kernel(const uint32_t* __restrict__ PTpad,
                                                    const float* __restrict__ w3T,
                                                    float* __restrict__ z) {
  int tid = threadIdx.x;
  int t = blockIdx.x * 256 + tid;
  int b = blockIdx.y;
  const uint4* pt = (const uint4*)PTpad + (size_t)b * (T_ + 1);
  uint4 R0 = pt[t];
  uint4 R1 = pt[t + 1];
  uint32_t r0w[4] = {R0.x, R0.y, R0.z, R0.w};
  uint32_t r1w[4] = {R1.x, R1.y, R1.z, R1.w};

  float acc[NOUT_];
#pragma unroll
  for (int o = 0; o < NOUT_; o++) acc[o] = 0.f;

#pragma unroll
  for (int c = 0; c < NH_; c++) {
    const float* wc = w3T + (c << 3);
    float f = wc[5], omf = wc[6];
    float fb0 = (float)((r0w[c >> 5] >> (c & 31)) & 1u);
    float fb1 = (float)((r1w[c >> 5] >> (c & 31)) & 1u);
    float val = __fmaf_rn(omf, fb1, __fmul_rn(f, fb0));
#pragma unroll
    for (int o = 0; o < NOUT_; o++) acc[o] = __fmaf_rn(wc[o], val, acc[o]);
  }

#pragma unroll
  for (int o = 0; o < NOUT_; o++)
    z[((size_t)b * NOUT_ + o) * T_ + t] = acc[o];
}

// ---------------------------------------------------------------------------
// Chunked layer-3 scan: thread per (chunk, b, o); 96-step warmup; f32 SHIFTED
// output (out[t]=s[t-1]) via float4 stores; count excludes t=T-1.
// ---------------------------------------------------------------------------
__global__ __launch_bounds__(256) void scan3_kernel(const float* __restrict__ z3,
                                                    float* __restrict__ out,
                                                    float* __restrict__ cnt) {
  int id = blockIdx.x * 256 + threadIdx.x;
  int row = id % (B_ * NOUT_);
  int ci = id / (B_ * NOUT_);
  int tstart = ci * CHT_;
  int t0 = (ci == 0) ? 0 : tstart - WARM_;
  const float4* zp4 = (const float4*)(z3 + (size_t)row * T_);

  float u = 0.f, v = 0.f, carry = 0.f;
  int cnt_i = 0;
  for (int gg = t0 / 16; gg < tstart / 16; gg++) {
#pragma unroll
    for (int q = 0; q < 4; q++) {
      float4 cv = zp4[gg * 4 + q];
      float zv[4] = {cv.x, cv.y, cv.z, cv.w};
#pragma unroll
      for (int j = 0; j < 4; j++) {
        u = addrn(mulrn(ALPHA_I_, u), zv[j]);
        v = addrn(mulrn(ALPHA_V_, v), u);
        bool s = (v >= THETA_);
        v = s ? 0.f : v;
        carry = s ? 1.f : 0.f;
      }
    }
  }
  float4* op4 = (float4*)(out + (size_t)row * T_ + tstart);
  for (int gg = 0; gg < CHT_ / 16; gg++) {
    float sarr[16];
#pragma unroll
    for (int q = 0; q < 4; q++) {
      float4 cv = zp4[(tstart / 16 + gg) * 4 + q];
      float zv[4] = {cv.x, cv.y, cv.z, cv.w};
#pragma unroll
      for (int j = 0; j < 4; j++) {
        u = addrn(mulrn(ALPHA_I_, u), zv[j]);
        v = addrn(mulrn(ALPHA_V_, v), u);
        bool s = (v >= THETA_);
        v = s ? 0.f : v;
        sarr[q * 4 + j] = s ? 1.f : 0.f;
      }
    }
#pragma unroll
    for (int k = 0; k < 16; k++) {
      int t = tstart + gg * 16 + k;
      if (t < T_ - 1) cnt_i += (sarr[k] != 0.f) ? 1 : 0;
    }
    op4[gg * 4 + 0] = make_float4(carry, sarr[0], sarr[1], sarr[2]);
    op4[gg * 4 + 1] = make_float4(sarr[3], sarr[4], sarr[5], sarr[6]);
    op4[gg * 4 + 2] = make_float4(sarr[7], sarr[8], sarr[9], sarr[10]);
    op4[gg * 4 + 3] = make_float4(sarr[11], sarr[12], sarr[13], sarr[14]);
    carry = sarr[15];
  }
  float c = (float)cnt_i;
  for (int off = 32; off; off >>= 1) c += __shfl_down(c, off, 64);
  if ((threadIdx.x & 63) == 0) atomicAdd(cnt, c);
}

// ---------------------------------------------------------------------------
extern "C" void kernel_launch(void* const* d_in, const int* in_sizes, int n_in,
                              void* d_out, int out_size, void* d_ws, size_t ws_size,
                              hipStream_t stream) {
  (void)in_sizes; (void)n_in; (void)out_size; (void)ws_size;
  const float* spike  = (const float*)d_in[0];
  const float* fc1_v  = (const float*)d_in[1];
  const float* fc1_g  = (const float*)d_in[2];
  const float* fc2_v  = (const float*)d_in[3];
  const float* fc2_g  = (const float*)d_in[4];
  const float* fc3_v  = (const float*)d_in[5];
  const float* fc3_g  = (const float*)d_in[6];
  const float* delay1 = (const float*)d_in[7];
  const float* delay2 = (const float*)d_in[8];
  float* out = (float*)d_out;

  float* ws = (float*)d_ws;
  float* w3T       = ws;                         // 1024 f
  float4* efo1     = (float4*)(ws + 1024);       // 512 f
  float4* efo2     = (float4*)(ws + 1536);       // 512 f
  uint16_t* w1swz  = (uint16_t*)(ws + 2048);     // 2048 u16 = 1024 f
  uint16_t* wswz   = (uint16_t*)(ws + 3072);     // 32768 u16 = 16384 f
  uint16_t* Xb     = (uint16_t*)(ws + 19456);    // B*T u16 = 131072 f
  uint32_t* sbits2 = (uint32_t*)(ws + 150528);   // B*68*128 u32
  uint32_t* PTpad  = (uint32_t*)(ws + 1264640);  // B*(T+1)*4 u32, 16B-aligned
  float* z3        = ws + 2313728;               // B*5*T f32
  float* counts = out + (size_t)B_ * NOUT_ * T_;

  prep_kernel<<<1, 1024, 0, stream>>>(fc1_v, fc1_g, fc2_v, fc2_g, fc3_v, fc3_g,
                                      delay1, delay2, w1swz, wswz, w3T, efo1, efo2, counts);

  pack_kernel<<<dim3(B_ * T_ / 64 / 4), 256, 0, stream>>>(spike, Xb);

  fused_layer1<<<dim3(NCHUNK_, B_), 128, 0, stream>>>(Xb, w1swz, sbits2, counts + 0);
  transpose_kernel<<<dim3(T_ / 256, B_), 256, 0, stream>>>(sbits2, efo1, PTpad);

  fused_layer2<<<dim3(NCHUNK_ / 8, 2, B_), 512, 0, stream>>>(PTpad, wswz, sbits2, counts + 1);
  transpose_kernel<<<dim3(T_ / 256, B_), 256, 0, stream>>>(sbits2, efo2, PTpad);

  gemm3_kernel<<<dim3(T_ / 256, B_), 256, 0, stream>>>(PTpad, w3T, z3);
  scan3_kernel<<<dim3(NCHUNK_ * B_ * NOUT_ / 256), 256, 0, stream>>>(z3, out, counts + 2);
}

// Round 12
// 289.053 us; speedup vs baseline: 1.1691x; 1.1691x over previous
//
#include <hip/hip_runtime.h>
#include <cstdint>

#define B_    128
#define T_    2048
#define NIN_  16
#define NH_   128
#define NOUT_ 5

#define ALPHA_I_ 0.75f
#define ALPHA_V_ 0.96875f
#define THETA_   64.0f

#define NCHUNK_ 8
#define CHT_    256     // data timesteps per chunk
#define WARM_   96      // warmup timesteps (3 sub-chunks of 32)

typedef short bf16x8 __attribute__((ext_vector_type(8)));
typedef float f32x16 __attribute__((ext_vector_type(16)));

__device__ __forceinline__ float mulrn(float a, float b) { return __fmul_rn(a, b); }
__device__ __forceinline__ float addrn(float a, float b) { return __fadd_rn(a, b); }

__device__ __forceinline__ uint16_t f2bf(float x) {  // RNE f32->bf16
  uint32_t u = __float_as_uint(x);
  return (uint16_t)((u + 0x7FFFu + ((u >> 16) & 1u)) >> 16);
}

// nibble LUT (16 x uint2 in LDS, bank-conflict-free): bit j -> bf16 1.0/0.0
__device__ __forceinline__ bf16x8 expand8(const uint2* __restrict__ lut, uint32_t byt) {
  uint2 lo = lut[byt & 15u];
  uint2 h  = lut[byt >> 4];
  union { uint32_t w[4]; bf16x8 f; } r;
  r.w[0] = lo.x; r.w[1] = lo.y; r.w[2] = h.x; r.w[3] = h.y;
  return r.f;
}

__device__ __forceinline__ void lut_init(uint2* s_lut, int tid) {
  if (tid < 16) {
    uint32_t w0 = ((tid & 1) ? 0x3F80u : 0u) | ((tid & 2) ? 0x3F800000u : 0u);
    uint32_t w1 = ((tid & 4) ? 0x3F80u : 0u) | ((tid & 8) ? 0x3F800000u : 0u);
    s_lut[tid] = make_uint2(w0, w1);
  }
}

// ---------------------------------------------------------------------------
// prep (1024 threads, coalesced): row sumsq via 8 threads/row + shfl reduce;
// all swizzle writes spread over 1024 threads. Layouts identical to the
// R5-R10-verified ones. efo: e=floor(d)+1 (includes delay_shift1's +1).
// ---------------------------------------------------------------------------
__global__ __launch_bounds__(1024) void prep_kernel(
    const float* __restrict__ fc1_v, const float* __restrict__ fc1_g,
    const float* __restrict__ fc2_v, const float* __restrict__ fc2_g,
    const float* __restrict__ fc3_v, const float* __restrict__ fc3_g,
    const float* __restrict__ delay1, const float* __restrict__ delay2,
    uint16_t* __restrict__ w1swz, uint16_t* __restrict__ wswz,
    float* __restrict__ w3T, float4* __restrict__ efo1, float4* __restrict__ efo2,
    float* __restrict__ counts) {
  __shared__ float s_n1[NH_], s_n2[NH_], s_n3[8], s_g2[NH_];
  int tid = threadIdx.x;
  {
    int o = tid >> 3, sub = tid & 7;  // 1024 threads -> 128 rows x 8 lanes
    float ss = 0.f;
    for (int c = sub; c < NIN_; c += 8) { float v = fc1_v[o * NIN_ + c]; ss = __fmaf_rn(v, v, ss); }
    ss += __shfl_down(ss, 4, 64); ss += __shfl_down(ss, 2, 64); ss += __shfl_down(ss, 1, 64);
    if (sub == 0) s_n1[o] = sqrtf(ss);
    float ss2 = 0.f;
    for (int c = sub; c < NH_; c += 8) { float v = fc2_v[o * NH_ + c]; ss2 = __fmaf_rn(v, v, ss2); }
    ss2 += __shfl_down(ss2, 4, 64); ss2 += __shfl_down(ss2, 2, 64); ss2 += __shfl_down(ss2, 1, 64);
    if (sub == 0) s_n2[o] = sqrtf(ss2);
  }
  if (tid < NOUT_ * 8) {
    int o = tid >> 3, sub = tid & 7;
    float ss = 0.f;
    for (int c = sub; c < NH_; c += 8) { float v = fc3_v[o * NH_ + c]; ss = __fmaf_rn(v, v, ss); }
    ss += __shfl_down(ss, 4, 64); ss += __shfl_down(ss, 2, 64); ss += __shfl_down(ss, 1, 64);
    if (sub == 0) s_n3[o] = sqrtf(ss);
  }
  if (tid < NH_) s_g2[tid] = fc2_g[tid];
  if (tid < 3) counts[tid] = 0.f;
  __syncthreads();

  if (tid < NH_) {
    float d1 = delay1[tid];
    float fl = floorf(d1);
    float f = __fsub_rn(d1, fl);
    efo1[tid] = make_float4(__int_as_float((int)fl + 1), f, __fsub_rn(1.0f, f), 0.f);
    float d2 = delay2[tid];
    float fl2 = floorf(d2);
    float f2v = __fsub_rn(d2, fl2);
    efo2[tid] = make_float4(__int_as_float((int)fl2 + 1), f2v, __fsub_rn(1.0f, f2v), 0.f);
    w3T[tid * 8 + 5] = f2v;
    w3T[tid * 8 + 6] = __fsub_rn(1.0f, f2v);
    w3T[tid * 8 + 7] = 0.f;
  }
  // layer-1 swizzle (coalesced over i)
  for (int i = tid; i < NH_ * NIN_; i += 1024) {
    int o = i >> 4, c = i & 15;
    float wv = 64.0f * __fdiv_rn(mulrn(fc1_g[o], fc1_v[i]), s_n1[o]);
    int mt = o >> 5, lane = (o & 31) + 32 * ((c >> 3) & 1), j = c & 7;
    w1swz[(mt * 64 + lane) * 8 + j] = f2bf(wv);
  }
  // layer-2 swizzle (coalesced over i)
  for (int i = tid; i < NH_ * NH_; i += 1024) {
    int o = i >> 7, c = i & 127;
    float wv = 64.0f * __fdiv_rn(mulrn(s_g2[o], fc2_v[i]), s_n2[o]);
    float d1 = delay1[c];
    float f = __fsub_rn(d1, floorf(d1));
    int lane = (o & 31) + 32 * ((c >> 3) & 1);
    int ks = c >> 4, j = c & 7, mt = o >> 5;
    wswz[((size_t)((0 * 4 + mt) * 8 + ks) * 64 + lane) * 8 + j] = f2bf(__fmul_rn(wv, f));
    wswz[((size_t)((1 * 4 + mt) * 8 + ks) * 64 + lane) * 8 + j] =
        f2bf(__fmul_rn(wv, __fsub_rn(1.0f, f)));
  }
  // layer-3 weights
  for (int i = tid; i < NOUT_ * NH_; i += 1024) {
    int o = i / NH_, c = i & 127;
    float wv = 64.0f * __fdiv_rn(mulrn(fc3_g[o], fc3_v[i]), s_n3[o]);
    w3T[c * 8 + o] = wv;
  }
}

// ---------------------------------------------------------------------------
// pack: input f32 spikes (B,16,T) -> 16-bit channel masks Xb[b][t] via ballot.
// ---------------------------------------------------------------------------
__global__ __launch_bounds__(256) void pack_kernel(const float* __restrict__ spike,
                                                   uint16_t* __restrict__ Xb) {
  int gw = blockIdx.x * 4 + (threadIdx.x >> 6);
  int lane = threadIdx.x & 63;
  int b = gw >> 5;
  int t = (gw & 31) * 64 + lane;
  const float* sp = spike + (size_t)b * NIN_ * T_ + t;
  uint32_t mask = 0;
#pragma unroll
  for (int c = 0; c < NIN_; c++) {
    unsigned long long bal = __ballot(sp[(size_t)c * T_] != 0.f);
    mask |= (uint32_t)((bal >> lane) & 1ull) << c;
  }
  Xb[(size_t)b * T_ + t] = (uint16_t)mask;
}

// ---------------------------------------------------------------------------
// Gather a wave's 2-tile (tiles A,B; 64o x 32t) MFMA result so that every
// lane holds all 32 t for one o, via 16 batched shfl_xor(32) (NOT in the
// scan chain). D layout (R6-R10-verified): row t = (r&3)+8*(r>>2)+4*hi,
// col o = lane&31. Then scan 32 steps fully in-register; o = pair*64+lane.
// ---------------------------------------------------------------------------
#define GATHER_AND_SCAN(aA, aB, hi, u, v, m)                               \
  {                                                                        \
    float evenQ[16], oddQ[16];                                             \
    _Pragma("unroll") for (int r = 0; r < 16; r++) {                       \
      float tmp = hi ? aA[r] : aB[r];                                      \
      float rcv = __shfl_xor(tmp, 32, 64);                                 \
      evenQ[r] = hi ? rcv : aA[r];                                         \
      oddQ[r] = hi ? aB[r] : rcv;                                          \
    }                                                                      \
    m = 0u;                                                                \
    _Pragma("unroll") for (int t = 0; t < 32; t++) {                       \
      int q = t >> 2;                                                      \
      int base = 4 * (q >> 1) + (t & 3);                                   \
      float z = (q & 1) ? oddQ[base] : evenQ[base];                        \
      u = addrn(mulrn(ALPHA_I_, u), z);                                    \
      v = addrn(mulrn(ALPHA_V_, v), u);                                    \
      bool sbit = (v >= THETA_);                                           \
      v = sbit ? 0.f : v;                                                  \
      m |= sbit ? (1u << t) : 0u;                                          \
    }                                                                      \
  }

// ---------------------------------------------------------------------------
// Fused layer 1: wave = 2 o-tiles (shared A-frag from input bits, 2 MFMA),
// gather + in-register scan, coalesced bit store + counts. Waves independent.
// grid (NCHUNK_, B), block 128. (128,4): cap 128 VGPR >= ~108 body, no spill.
// ---------------------------------------------------------------------------
__global__ __launch_bounds__(128, 4) void fused_layer1(const uint16_t* __restrict__ Xb,
                                                       const uint16_t* __restrict__ w1swz,
                                                       uint32_t* __restrict__ sbits2,
                                                       float* __restrict__ cnt) {
  __shared__ uint2 s_lut[16];
  int tid = threadIdx.x;
  int pair = tid >> 6, lane = tid & 63;
  int hi = lane >> 5, tl = lane & 31;
  int ci = blockIdx.x, b = blockIdx.y;
  lut_init(s_lut, tid);
  const bf16x8* w1v = (const bf16x8*)w1swz;
  bf16x8 wA = w1v[(pair * 2 + 0) * 64 + lane];
  bf16x8 wB = w1v[(pair * 2 + 1) * 64 + lane];
  __syncthreads();

  int wch = (ci == 0) ? 0 : (WARM_ / 32);
  int nch = CHT_ / 32 + wch;
  int chbase0 = ci * CHT_ - wch * 32;
  const uint16_t* xb = Xb + (size_t)b * T_;
  uint32_t* sb = sbits2 + (size_t)b * 68 * NH_;

  float u = 0.f, v = 0.f, csum = 0.f;
  uint32_t x = xb[chbase0 + tl];
  for (int g = 0; g < nch; g++) {
    uint32_t xn = (g + 1 < nch) ? (uint32_t)xb[chbase0 + (g + 1) * 32 + tl] : 0u;
    uint32_t byt = (x >> (8 * hi)) & 0xFFu;
    bf16x8 e = expand8(s_lut, byt);
    f32x16 aA, aB;
#pragma unroll
    for (int r = 0; r < 16; r++) { aA[r] = 0.f; aB[r] = 0.f; }
    aA = __builtin_amdgcn_mfma_f32_32x32x16_bf16(e, wA, aA, 0, 0, 0);
    aB = __builtin_amdgcn_mfma_f32_32x32x16_bf16(e, wB, aB, 0, 0, 0);
    uint32_t m;
    GATHER_AND_SCAN(aA, aB, hi, u, v, m);
    if (g >= wch) {
      int gw = (chbase0 + g * 32) >> 5;
      sb[(2 + gw) * NH_ + pair * 64 + lane] = m;
      int pc = __popc(m);
      if (gw == 63) pc -= (int)(m >> 31);
      csum += (float)pc;
    }
    x = xn;
  }
  if (ci == 0) { sb[0 * NH_ + pair * 64 + lane] = 0u; sb[1 * NH_ + pair * 64 + lane] = 0u; }
  if (ci == NCHUNK_ - 1) { sb[66 * NH_ + pair * 64 + lane] = 0u; sb[67 * NH_ + pair * 64 + lane] = 0u; }
  for (int off = 32; off; off >>= 1) csum += __shfl_down(csum, off, 64);
  if (lane == 0) atomicAdd(cnt, csum);
}

// ---------------------------------------------------------------------------
// Fused layer 2: block = 4 waves of the SAME o-pair (pb), chunks bx*4..bx*4+3.
// Weight fragments staged ONCE into 32 KB LDS shared by the 4 waves.
// (256,4): cap 128 VGPR >= R10's measured 124 body -> no spill, 4 waves/SIMD
// (4 blocks/CU, 132 KB LDS). Per ks: 4 ds_read_b128 + 2 LUT expands + 4 MFMA.
// grid (NCHUNK_/4, 2, B), block 256. Barrier-free main loop.
// ---------------------------------------------------------------------------
__global__ __launch_bounds__(256, 4) void fused_layer2(const uint32_t* __restrict__ PTpad,
                                                       const uint16_t* __restrict__ wswz,
                                                       uint32_t* __restrict__ sbits2,
                                                       float* __restrict__ cnt) {
  __shared__ uint16_t s_w[4 * 8 * 64 * 8];  // [arr][ks][lane][j], 32 KB
  __shared__ uint2 s_lut[16];
  int tid = threadIdx.x;
  int wv = tid >> 6, lane = tid & 63;
  int hi = lane >> 5, tl = lane & 31;
  int pb = blockIdx.y, b = blockIdx.z;
  int ci = blockIdx.x * 4 + wv;
  lut_init(s_lut, tid);
  {
    // arr: 0=WfA 1=WofA 2=WfB 3=WofB  (A: mt=2pb, B: mt=2pb+1)
    const uint4* wsrc = (const uint4*)wswz;
    uint4* wdst = (uint4*)s_w;
    for (int i = tid; i < 2048; i += 256) {
      int arr = i >> 9, rest = i & 511;      // rest = ks*64 + lane
      int half = arr & 1, mt = 2 * pb + (arr >> 1);
      wdst[i] = wsrc[(size_t)((half * 4 + mt) * 8) * 64 + rest];
    }
  }
  __syncthreads();

  int wch = (ci == 0) ? 0 : (WARM_ / 32);
  int nch = CHT_ / 32 + wch;
  int chbase0 = ci * CHT_ - wch * 32;
  const uint4* pt = (const uint4*)PTpad + (size_t)b * (T_ + 1);
  uint32_t* sb = sbits2 + (size_t)b * 68 * NH_;
  const bf16x8* wlds = (const bf16x8*)s_w;

  float u = 0.f, v = 0.f, csum = 0.f;
  uint4 R0 = pt[chbase0 + tl];
  uint4 R1 = pt[chbase0 + tl + 1];
  for (int g = 0; g < nch; g++) {
    uint4 R0n = R0, R1n = R1;
    if (g + 1 < nch) {
      R0n = pt[chbase0 + (g + 1) * 32 + tl];
      R1n = pt[chbase0 + (g + 1) * 32 + tl + 1];
    }
    uint32_t r0w[4] = {R0.x, R0.y, R0.z, R0.w};
    uint32_t r1w[4] = {R1.x, R1.y, R1.z, R1.w};
    f32x16 aA, aB;
#pragma unroll
    for (int r = 0; r < 16; r++) { aA[r] = 0.f; aB[r] = 0.f; }
#pragma unroll
    for (int ks = 0; ks < 8; ks++) {
      int sh = 16 * (ks & 1) + 8 * hi;
      uint32_t b0 = (r0w[ks >> 1] >> sh) & 0xFFu;  // tap s[t-e-1] -> Wf
      uint32_t b1 = (r1w[ks >> 1] >> sh) & 0xFFu;  // tap s[t-e]   -> Wof
      bf16x8 e0 = expand8(s_lut, b0);
      bf16x8 e1 = expand8(s_lut, b1);
      bf16x8 wfA = wlds[0 * 512 + ks * 64 + lane];
      bf16x8 woA = wlds[1 * 512 + ks * 64 + lane];
      bf16x8 wfB = wlds[2 * 512 + ks * 64 + lane];
      bf16x8 woB = wlds[3 * 512 + ks * 64 + lane];
      aA = __builtin_amdgcn_mfma_f32_32x32x16_bf16(e0, wfA, aA, 0, 0, 0);
      aA = __builtin_amdgcn_mfma_f32_32x32x16_bf16(e1, woA, aA, 0, 0, 0);
      aB = __builtin_amdgcn_mfma_f32_32x32x16_bf16(e0, wfB, aB, 0, 0, 0);
      aB = __builtin_amdgcn_mfma_f32_32x32x16_bf16(e1, woB, aB, 0, 0, 0);
    }
    uint32_t m;
    GATHER_AND_SCAN(aA, aB, hi, u, v, m);
    if (g >= wch) {
      int gw = (chbase0 + g * 32) >> 5;
      sb[(2 + gw) * NH_ + pb * 64 + lane] = m;
      int pc = __popc(m);
      if (gw == 63) pc -= (int)(m >> 31);
      csum += (float)pc;
    }
    R0 = R0n; R1 = R1n;
  }
  if (ci == 0) { sb[0 * NH_ + pb * 64 + lane] = 0u; sb[1 * NH_ + pb * 64 + lane] = 0u; }
  if (ci == NCHUNK_ - 1) { sb[66 * NH_ + pb * 64 + lane] = 0u; sb[67 * NH_ + pb * 64 + lane] = 0u; }
  for (int off = 32; off; off >>= 1) csum += __shfl_down(csum, off, 64);
  if (lane == 0) atomicAdd(cnt, csum);
}

// ---------------------------------------------------------------------------
// bit transpose + delay pre-shift: grid (T/256, B); one t per thread.
// 10-word LDS window per channel; per-c funnel read as one unaligned 8B
// access (-> ds_read2_b32). PTpad[b][1+t] bit c = s[c][t-e_c]; PTpad[b][0]=0.
// ---------------------------------------------------------------------------
__global__ __launch_bounds__(256) void transpose_kernel(const uint32_t* __restrict__ sbits2,
                                                        const float4* __restrict__ efo,
                                                        uint32_t* __restrict__ PTpad) {
  __shared__ uint32_t rows[NH_][11];  // k=0..9 (+1 pad)
  int tid = threadIdx.x;
  int b = blockIdx.y;
  int t0blk = blockIdx.x * 256;
  int w0 = t0blk >> 5;
  const uint32_t* src = sbits2 + (size_t)b * 68 * NH_;
  for (int i = tid; i < NH_ * 10; i += 256) {
    int k = i >> 7, c = i & 127;
    rows[c][k] = src[(1 + w0 + k) * NH_ + c];  // slot 1+w0+k (guards at 0,1,66,67)
  }
  __syncthreads();

  int t = t0blk + tid;
  uint32_t wacc[4] = {0u, 0u, 0u, 0u};
#pragma unroll
  for (int c = 0; c < NH_; c++) {
    int e = __float_as_int(efo[c].x);           // uniform -> scalar load
    int bitpos = t - e;                          // >= t0blk-11
    int wi = (bitpos >> 5) - w0 + 1;             // in [0, 9]
    int sh = bitpos & 31;
    uint2 w2;
    __builtin_memcpy(&w2, &rows[c][wi], 8);      // unaligned 8B -> ds_read2_b32
    uint32_t bit = (uint32_t)(((((unsigned long long)w2.y << 32) | w2.x) >> sh)) & 1u;
    wacc[c >> 5] |= bit << (c & 31);
  }
  uint4* outp = (uint4*)PTpad + (size_t)b * (T_ + 1);
  outp[1 + t] = make_uint4(wacc[0], wacc[1], wacc[2], wacc[3]);
  if (t == 0) outp[0] = make_uint4(0u, 0u, 0u, 0u);
}

// ---------------------------------------------------------------------------
// gemm3 (vector): 5 outputs from pre-shifted PT rows.
// ---------------------------------------------------------------------------
__global__ __launch_bounds__(256) void gemm3_kernel(const uint32_t* __restrict__ PTpad,
                                                    const float* __restrict__ w3T,
                                                    float* __restrict__ z) {
  int tid = threadIdx.x;
  int t = blockIdx.x * 256 + tid;
  int b = blockIdx.y;
  const uint4* pt = (const uint4*)PTpad + (size_t)b * (T_ + 1);
  uint4 R0 = pt[t];
  uint4 R1 = pt[t + 1];
  uint32_t r0w[4] = {R0.x, R0.y, R0.z, R0.w};
  uint32_t r1w[4] = {R1.x, R1.y, R1.z, R1.w};

  float acc[NOUT_];
#pragma unroll
  for (int o = 0; o < NOUT_; o++) acc[o] = 0.f;

#pragma unroll
  for (int c = 0; c < NH_; c++) {
    const float* wc = w3T + (c << 3);
    float f = wc[5], omf = wc[6];
    float fb0 = (float)((r0w[c >> 5] >> (c & 31)) & 1u);
    float fb1 = (float)((r1w[c >> 5] >> (c & 31)) & 1u);
    float val = __fmaf_rn(omf, fb1, __fmul_rn(f, fb0));
#pragma unroll
    for (int o = 0; o < NOUT_; o++) acc[o] = __fmaf_rn(wc[o], val, acc[o]);
  }

#pragma unroll
  for (int o = 0; o < NOUT_; o++)
    z[((size_t)b * NOUT_ + o) * T_ + t] = acc[o];
}

// ---------------------------------------------------------------------------
// Chunked layer-3 scan: thread per (chunk, b, o); 96-step warmup; f32 SHIFTED
// output (out[t]=s[t-1]) via float4 stores; count excludes t=T-1.
// ---------------------------------------------------------------------------
__global__ __launch_bounds__(256) void scan3_kernel(const float* __restrict__ z3,
                                                    float* __restrict__ out,
                                                    float* __restrict__ cnt) {
  int id = blockIdx.x * 256 + threadIdx.x;
  int row = id % (B_ * NOUT_);
  int ci = id / (B_ * NOUT_);
  int tstart = ci * CHT_;
  int t0 = (ci == 0) ? 0 : tstart - WARM_;
  const float4* zp4 = (const float4*)(z3 + (size_t)row * T_);

  float u = 0.f, v = 0.f, carry = 0.f;
  int cnt_i = 0;
  for (int gg = t0 / 16; gg < tstart / 16; gg++) {
#pragma unroll
    for (int q = 0; q < 4; q++) {
      float4 cv = zp4[gg * 4 + q];
      float zv[4] = {cv.x, cv.y, cv.z, cv.w};
#pragma unroll
      for (int j = 0; j < 4; j++) {
        u = addrn(mulrn(ALPHA_I_, u), zv[j]);
        v = addrn(mulrn(ALPHA_V_, v), u);
        bool s = (v >= THETA_);
        v = s ? 0.f : v;
        carry = s ? 1.f : 0.f;
      }
    }
  }
  float4* op4 = (float4*)(out + (size_t)row * T_ + tstart);
  for (int gg = 0; gg < CHT_ / 16; gg++) {
    float sarr[16];
#pragma unroll
    for (int q = 0; q < 4; q++) {
      float4 cv = zp4[(tstart / 16 + gg) * 4 + q];
      float zv[4] = {cv.x, cv.y, cv.z, cv.w};
#pragma unroll
      for (int j = 0; j < 4; j++) {
        u = addrn(mulrn(ALPHA_I_, u), zv[j]);
        v = addrn(mulrn(ALPHA_V_, v), u);
        bool s = (v >= THETA_);
        v = s ? 0.f : v;
        sarr[q * 4 + j] = s ? 1.f : 0.f;
      }
    }
#pragma unroll
    for (int k = 0; k < 16; k++) {
      int t = tstart + gg * 16 + k;
      if (t < T_ - 1) cnt_i += (sarr[k] != 0.f) ? 1 : 0;
    }
    op4[gg * 4 + 0] = make_float4(carry, sarr[0], sarr[1], sarr[2]);
    op4[gg * 4 + 1] = make_float4(sarr[3], sarr[4], sarr[5], sarr[6]);
    op4[gg * 4 + 2] = make_float4(sarr[7], sarr[8], sarr[9], sarr[10]);
    op4[gg * 4 + 3] = make_float4(sarr[11], sarr[12], sarr[13], sarr[14]);
    carry = sarr[15];
  }
  float c = (float)cnt_i;
  for (int off = 32; off; off >>= 1) c += __shfl_down(c, off, 64);
  if ((threadIdx.x & 63) == 0) atomicAdd(cnt, c);
}

// ---------------------------------------------------------------------------
extern "C" void kernel_launch(void* const* d_in, const int* in_sizes, int n_in,
                              void* d_out, int out_size, void* d_ws, size_t ws_size,
                              hipStream_t stream) {
  (void)in_sizes; (void)n_in; (void)out_size; (void)ws_size;
  const float* spike  = (const float*)d_in[0];
  const float* fc1_v  = (const float*)d_in[1];
  const float* fc1_g  = (const float*)d_in[2];
  const float* fc2_v  = (const float*)d_in[3];
  const float* fc2_g  = (const float*)d_in[4];
  const float* fc3_v  = (const float*)d_in[5];
  const float* fc3_g  = (const float*)d_in[6];
  const float* delay1 = (const float*)d_in[7];
  const float* delay2 = (const float*)d_in[8];
  float* out = (float*)d_out;

  float* ws = (float*)d_ws;
  float* w3T       = ws;                         // 1024 f
  float4* efo1     = (float4*)(ws + 1024);       // 512 f
  float4* efo2     = (float4*)(ws + 1536);       // 512 f
  uint16_t* w1swz  = (uint16_t*)(ws + 2048);     // 2048 u16 = 1024 f
  uint16_t* wswz   = (uint16_t*)(ws + 3072);     // 32768 u16 = 16384 f
  uint16_t* Xb     = (uint16_t*)(ws + 19456);    // B*T u16 = 131072 f
  uint32_t* sbits2 = (uint32_t*)(ws + 150528);   // B*68*128 u32
  uint32_t* PTpad  = (uint32_t*)(ws + 1264640);  // B*(T+1)*4 u32, 16B-aligned
  float* z3        = ws + 2313728;               // B*5*T f32
  float* counts = out + (size_t)B_ * NOUT_ * T_;

  prep_kernel<<<1, 1024, 0, stream>>>(fc1_v, fc1_g, fc2_v, fc2_g, fc3_v, fc3_g,
                                      delay1, delay2, w1swz, wswz, w3T, efo1, efo2, counts);

  pack_kernel<<<dim3(B_ * T_ / 64 / 4), 256, 0, stream>>>(spike, Xb);

  fused_layer1<<<dim3(NCHUNK_, B_), 128, 0, stream>>>(Xb, w1swz, sbits2, counts + 0);
  transpose_kernel<<<dim3(T_ / 256, B_), 256, 0, stream>>>(sbits2, efo1, PTpad);

  fused_layer2<<<dim3(NCHUNK_ / 4, 2, B_), 256, 0, stream>>>(PTpad, wswz, sbits2, counts + 1);
  transpose_kernel<<<dim3(T_ / 256, B_), 256, 0, stream>>>(sbits2, efo2, PTpad);

  gemm3_kernel<<<dim3(T_ / 256, B_), 256, 0, stream>>>(PTpad, w3T, z3);
  scan3_kernel<<<dim3(NCHUNK_ * B_ * NOUT_ / 256), 256, 0, stream>>>(z3, out, counts + 2);
}

// Round 13
// 245.985 us; speedup vs baseline: 1.3738x; 1.1751x over previous
//
#include <hip/hip_runtime.h>
#include <cstdint>

#define B_    128
#define T_    2048
#define NIN_  16
#define NH_   128
#define NOUT_ 5

#define ALPHA_I_ 0.75f
#define ALPHA_V_ 0.96875f
#define THETA_   64.0f

#define NCHUNK_ 8
#define CHT_    256     // data timesteps per chunk
#define WARM_   96      // warmup timesteps (3 sub-chunks of 32)

typedef short bf16x8 __attribute__((ext_vector_type(8)));
typedef float f32x16 __attribute__((ext_vector_type(16)));

__device__ __forceinline__ float mulrn(float a, float b) { return __fmul_rn(a, b); }
__device__ __forceinline__ float addrn(float a, float b) { return __fadd_rn(a, b); }

__device__ __forceinline__ uint16_t f2bf(float x) {  // RNE f32->bf16
  uint32_t u = __float_as_uint(x);
  return (uint16_t)((u + 0x7FFFu + ((u >> 16) & 1u)) >> 16);
}

// nibble LUT (16 x uint2 in LDS, bank-conflict-free): bit j -> bf16 1.0/0.0
__device__ __forceinline__ bf16x8 expand8(const uint2* __restrict__ lut, uint32_t byt) {
  uint2 lo = lut[byt & 15u];
  uint2 h  = lut[byt >> 4];
  union { uint32_t w[4]; bf16x8 f; } r;
  r.w[0] = lo.x; r.w[1] = lo.y; r.w[2] = h.x; r.w[3] = h.y;
  return r.f;
}

__device__ __forceinline__ void lut_init(uint2* s_lut, int tid) {
  if (tid < 16) {
    uint32_t w0 = ((tid & 1) ? 0x3F80u : 0u) | ((tid & 2) ? 0x3F800000u : 0u);
    uint32_t w1 = ((tid & 4) ? 0x3F80u : 0u) | ((tid & 8) ? 0x3F800000u : 0u);
    s_lut[tid] = make_uint2(w0, w1);
  }
}

// ---------------------------------------------------------------------------
// prep (1024 threads, coalesced — R12-verified): row sumsq via 8 threads/row
// + shfl reduce; swizzle writes spread over 1024 threads. Layouts identical
// to R5-R12-verified. efo: e=floor(d)+1 (includes delay_shift1's +1).
// ---------------------------------------------------------------------------
__global__ __launch_bounds__(1024) void prep_kernel(
    const float* __restrict__ fc1_v, const float* __restrict__ fc1_g,
    const float* __restrict__ fc2_v, const float* __restrict__ fc2_g,
    const float* __restrict__ fc3_v, const float* __restrict__ fc3_g,
    const float* __restrict__ delay1, const float* __restrict__ delay2,
    uint16_t* __restrict__ w1swz, uint16_t* __restrict__ wswz,
    float* __restrict__ w3T, float4* __restrict__ efo1, float4* __restrict__ efo2,
    float* __restrict__ counts) {
  __shared__ float s_n1[NH_], s_n2[NH_], s_n3[8], s_g2[NH_];
  int tid = threadIdx.x;
  {
    int o = tid >> 3, sub = tid & 7;  // 1024 threads -> 128 rows x 8 lanes
    float ss = 0.f;
    for (int c = sub; c < NIN_; c += 8) { float v = fc1_v[o * NIN_ + c]; ss = __fmaf_rn(v, v, ss); }
    ss += __shfl_down(ss, 4, 64); ss += __shfl_down(ss, 2, 64); ss += __shfl_down(ss, 1, 64);
    if (sub == 0) s_n1[o] = sqrtf(ss);
    float ss2 = 0.f;
    for (int c = sub; c < NH_; c += 8) { float v = fc2_v[o * NH_ + c]; ss2 = __fmaf_rn(v, v, ss2); }
    ss2 += __shfl_down(ss2, 4, 64); ss2 += __shfl_down(ss2, 2, 64); ss2 += __shfl_down(ss2, 1, 64);
    if (sub == 0) s_n2[o] = sqrtf(ss2);
  }
  if (tid < NOUT_ * 8) {
    int o = tid >> 3, sub = tid & 7;
    float ss = 0.f;
    for (int c = sub; c < NH_; c += 8) { float v = fc3_v[o * NH_ + c]; ss = __fmaf_rn(v, v, ss); }
    ss += __shfl_down(ss, 4, 64); ss += __shfl_down(ss, 2, 64); ss += __shfl_down(ss, 1, 64);
    if (sub == 0) s_n3[o] = sqrtf(ss);
  }
  if (tid < NH_) s_g2[tid] = fc2_g[tid];
  if (tid < 3) counts[tid] = 0.f;
  __syncthreads();

  if (tid < NH_) {
    float d1 = delay1[tid];
    float fl = floorf(d1);
    float f = __fsub_rn(d1, fl);
    efo1[tid] = make_float4(__int_as_float((int)fl + 1), f, __fsub_rn(1.0f, f), 0.f);
    float d2 = delay2[tid];
    float fl2 = floorf(d2);
    float f2v = __fsub_rn(d2, fl2);
    efo2[tid] = make_float4(__int_as_float((int)fl2 + 1), f2v, __fsub_rn(1.0f, f2v), 0.f);
    w3T[tid * 8 + 5] = f2v;
    w3T[tid * 8 + 6] = __fsub_rn(1.0f, f2v);
    w3T[tid * 8 + 7] = 0.f;
  }
  for (int i = tid; i < NH_ * NIN_; i += 1024) {
    int o = i >> 4, c = i & 15;
    float wv = 64.0f * __fdiv_rn(mulrn(fc1_g[o], fc1_v[i]), s_n1[o]);
    int mt = o >> 5, lane = (o & 31) + 32 * ((c >> 3) & 1), j = c & 7;
    w1swz[(mt * 64 + lane) * 8 + j] = f2bf(wv);
  }
  for (int i = tid; i < NH_ * NH_; i += 1024) {
    int o = i >> 7, c = i & 127;
    float wv = 64.0f * __fdiv_rn(mulrn(s_g2[o], fc2_v[i]), s_n2[o]);
    float d1 = delay1[c];
    float f = __fsub_rn(d1, floorf(d1));
    int lane = (o & 31) + 32 * ((c >> 3) & 1);
    int ks = c >> 4, j = c & 7, mt = o >> 5;
    wswz[((size_t)((0 * 4 + mt) * 8 + ks) * 64 + lane) * 8 + j] = f2bf(__fmul_rn(wv, f));
    wswz[((size_t)((1 * 4 + mt) * 8 + ks) * 64 + lane) * 8 + j] =
        f2bf(__fmul_rn(wv, __fsub_rn(1.0f, f)));
  }
  for (int i = tid; i < NOUT_ * NH_; i += 1024) {
    int o = i / NH_, c = i & 127;
    float wv = 64.0f * __fdiv_rn(mulrn(fc3_g[o], fc3_v[i]), s_n3[o]);
    w3T[c * 8 + o] = wv;
  }
}

// ---------------------------------------------------------------------------
// pack: input f32 spikes (B,16,T) -> 16-bit channel masks Xb[b][t] via ballot.
// ---------------------------------------------------------------------------
__global__ __launch_bounds__(256) void pack_kernel(const float* __restrict__ spike,
                                                   uint16_t* __restrict__ Xb) {
  int gw = blockIdx.x * 4 + (threadIdx.x >> 6);
  int lane = threadIdx.x & 63;
  int b = gw >> 5;
  int t = (gw & 31) * 64 + lane;
  const float* sp = spike + (size_t)b * NIN_ * T_ + t;
  uint32_t mask = 0;
#pragma unroll
  for (int c = 0; c < NIN_; c++) {
    unsigned long long bal = __ballot(sp[(size_t)c * T_] != 0.f);
    mask |= (uint32_t)((bal >> lane) & 1ull) << c;
  }
  Xb[(size_t)b * T_ + t] = (uint16_t)mask;
}

// ---------------------------------------------------------------------------
// Gather a wave's 2-tile (tiles A,B; 64o x 32t) MFMA result so that every
// lane holds all 32 t for one o, via 16 batched shfl_xor(32) (NOT in the
// scan chain). D layout (R6-R12-verified): row t = (r&3)+8*(r>>2)+4*hi,
// col o = lane&31. Then scan 32 steps fully in-register; o = pair*64+lane.
// ---------------------------------------------------------------------------
#define GATHER_AND_SCAN(aA, aB, hi, u, v, m)                               \
  {                                                                        \
    float evenQ[16], oddQ[16];                                             \
    _Pragma("unroll") for (int r = 0; r < 16; r++) {                       \
      float tmp = hi ? aA[r] : aB[r];                                      \
      float rcv = __shfl_xor(tmp, 32, 64);                                 \
      evenQ[r] = hi ? rcv : aA[r];                                         \
      oddQ[r] = hi ? aB[r] : rcv;                                          \
    }                                                                      \
    m = 0u;                                                                \
    _Pragma("unroll") for (int t = 0; t < 32; t++) {                       \
      int q = t >> 2;                                                      \
      int base = 4 * (q >> 1) + (t & 3);                                   \
      float z = (q & 1) ? oddQ[base] : evenQ[base];                        \
      u = addrn(mulrn(ALPHA_I_, u), z);                                    \
      v = addrn(mulrn(ALPHA_V_, v), u);                                    \
      bool sbit = (v >= THETA_);                                           \
      v = sbit ? 0.f : v;                                                  \
      m |= sbit ? (1u << t) : 0u;                                          \
    }                                                                      \
  }

// ---------------------------------------------------------------------------
// Fused layer 1 (R8/R10-verified, (128,2)): wave = 2 o-tiles (shared A-frag
// from input bits, 2 MFMA), gather + in-register scan, coalesced bit store.
// grid (NCHUNK_, B), block 128.
// ---------------------------------------------------------------------------
__global__ __launch_bounds__(128, 2) void fused_layer1(const uint16_t* __restrict__ Xb,
                                                       const uint16_t* __restrict__ w1swz,
                                                       uint32_t* __restrict__ sbits2,
                                                       float* __restrict__ cnt) {
  __shared__ uint2 s_lut[16];
  int tid = threadIdx.x;
  int pair = tid >> 6, lane = tid & 63;
  int hi = lane >> 5, tl = lane & 31;
  int ci = blockIdx.x, b = blockIdx.y;
  lut_init(s_lut, tid);
  const bf16x8* w1v = (const bf16x8*)w1swz;
  bf16x8 wA = w1v[(pair * 2 + 0) * 64 + lane];
  bf16x8 wB = w1v[(pair * 2 + 1) * 64 + lane];
  __syncthreads();

  int wch = (ci == 0) ? 0 : (WARM_ / 32);
  int nch = CHT_ / 32 + wch;
  int chbase0 = ci * CHT_ - wch * 32;
  const uint16_t* xb = Xb + (size_t)b * T_;
  uint32_t* sb = sbits2 + (size_t)b * 68 * NH_;

  float u = 0.f, v = 0.f, csum = 0.f;
  uint32_t x = xb[chbase0 + tl];
  for (int g = 0; g < nch; g++) {
    uint32_t xn = (g + 1 < nch) ? (uint32_t)xb[chbase0 + (g + 1) * 32 + tl] : 0u;
    uint32_t byt = (x >> (8 * hi)) & 0xFFu;
    bf16x8 e = expand8(s_lut, byt);
    f32x16 aA, aB;
#pragma unroll
    for (int r = 0; r < 16; r++) { aA[r] = 0.f; aB[r] = 0.f; }
    aA = __builtin_amdgcn_mfma_f32_32x32x16_bf16(e, wA, aA, 0, 0, 0);
    aB = __builtin_amdgcn_mfma_f32_32x32x16_bf16(e, wB, aB, 0, 0, 0);
    uint32_t m;
    GATHER_AND_SCAN(aA, aB, hi, u, v, m);
    if (g >= wch) {
      int gw = (chbase0 + g * 32) >> 5;
      sb[(2 + gw) * NH_ + pair * 64 + lane] = m;
      int pc = __popc(m);
      if (gw == 63) pc -= (int)(m >> 31);
      csum += (float)pc;
    }
    x = xn;
  }
  if (ci == 0) { sb[0 * NH_ + pair * 64 + lane] = 0u; sb[1 * NH_ + pair * 64 + lane] = 0u; }
  if (ci == NCHUNK_ - 1) { sb[66 * NH_ + pair * 64 + lane] = 0u; sb[67 * NH_ + pair * 64 + lane] = 0u; }
  for (int off = 32; off; off >>= 1) csum += __shfl_down(csum, off, 64);
  if (lane == 0) atomicAdd(cnt, csum);
}

// ---------------------------------------------------------------------------
// Fused layer 2 (R8-verified, 48.9 us, (128,2)): wave = 2 o-tiles, weight
// fragments in registers (VGPR 108, no spill at this bound), shared A-frags
// (2 delay taps from pre-shifted PT rows), 4 MFMA/ks.
// grid (NCHUNK_, B), block 128.
// ---------------------------------------------------------------------------
__global__ __launch_bounds__(128, 2) void fused_layer2(const uint32_t* __restrict__ PTpad,
                                                       const uint16_t* __restrict__ wswz,
                                                       uint32_t* __restrict__ sbits2,
                                                       float* __restrict__ cnt) {
  __shared__ uint2 s_lut[16];
  int tid = threadIdx.x;
  int pair = tid >> 6, lane = tid & 63;
  int hi = lane >> 5, tl = lane & 31;
  int ci = blockIdx.x, b = blockIdx.y;
  lut_init(s_lut, tid);
  const bf16x8* wsv = (const bf16x8*)wswz;
  int mtA = pair * 2, mtB = pair * 2 + 1;
  bf16x8 wfA[8], woA[8], wfB[8], woB[8];
#pragma unroll
  for (int ks = 0; ks < 8; ks++) {
    wfA[ks] = wsv[((size_t)((0 * 4 + mtA) * 8 + ks) * 64) + lane];
    woA[ks] = wsv[((size_t)((1 * 4 + mtA) * 8 + ks) * 64) + lane];
    wfB[ks] = wsv[((size_t)((0 * 4 + mtB) * 8 + ks) * 64) + lane];
    woB[ks] = wsv[((size_t)((1 * 4 + mtB) * 8 + ks) * 64) + lane];
  }
  __syncthreads();

  int wch = (ci == 0) ? 0 : (WARM_ / 32);
  int nch = CHT_ / 32 + wch;
  int chbase0 = ci * CHT_ - wch * 32;
  const uint4* pt = (const uint4*)PTpad + (size_t)b * (T_ + 1);
  uint32_t* sb = sbits2 + (size_t)b * 68 * NH_;

  float u = 0.f, v = 0.f, csum = 0.f;
  uint4 R0 = pt[chbase0 + tl];
  uint4 R1 = pt[chbase0 + tl + 1];
  for (int g = 0; g < nch; g++) {
    uint4 R0n = R0, R1n = R1;
    if (g + 1 < nch) {
      R0n = pt[chbase0 + (g + 1) * 32 + tl];
      R1n = pt[chbase0 + (g + 1) * 32 + tl + 1];
    }
    uint32_t r0w[4] = {R0.x, R0.y, R0.z, R0.w};
    uint32_t r1w[4] = {R1.x, R1.y, R1.z, R1.w};
    f32x16 aA, aB;
#pragma unroll
    for (int r = 0; r < 16; r++) { aA[r] = 0.f; aB[r] = 0.f; }
#pragma unroll
    for (int ks = 0; ks < 8; ks++) {
      int sh = 16 * (ks & 1) + 8 * hi;
      uint32_t b0 = (r0w[ks >> 1] >> sh) & 0xFFu;  // tap s[t-e-1] -> Wf
      uint32_t b1 = (r1w[ks >> 1] >> sh) & 0xFFu;  // tap s[t-e]   -> Wof
      bf16x8 e0 = expand8(s_lut, b0);
      bf16x8 e1 = expand8(s_lut, b1);
      aA = __builtin_amdgcn_mfma_f32_32x32x16_bf16(e0, wfA[ks], aA, 0, 0, 0);
      aA = __builtin_amdgcn_mfma_f32_32x32x16_bf16(e1, woA[ks], aA, 0, 0, 0);
      aB = __builtin_amdgcn_mfma_f32_32x32x16_bf16(e0, wfB[ks], aB, 0, 0, 0);
      aB = __builtin_amdgcn_mfma_f32_32x32x16_bf16(e1, woB[ks], aB, 0, 0, 0);
    }
    uint32_t m;
    GATHER_AND_SCAN(aA, aB, hi, u, v, m);
    if (g >= wch) {
      int gw = (chbase0 + g * 32) >> 5;
      sb[(2 + gw) * NH_ + pair * 64 + lane] = m;
      int pc = __popc(m);
      if (gw == 63) pc -= (int)(m >> 31);
      csum += (float)pc;
    }
    R0 = R0n; R1 = R1n;
  }
  if (ci == 0) { sb[0 * NH_ + pair * 64 + lane] = 0u; sb[1 * NH_ + pair * 64 + lane] = 0u; }
  if (ci == NCHUNK_ - 1) { sb[66 * NH_ + pair * 64 + lane] = 0u; sb[67 * NH_ + pair * 64 + lane] = 0u; }
  for (int off = 32; off; off >>= 1) csum += __shfl_down(csum, off, 64);
  if (lane == 0) atomicAdd(cnt, csum);
}

// ---------------------------------------------------------------------------
// bit transpose + delay pre-shift (R12-verified parallel version):
// grid (T/256, B); one t per thread; 10-word LDS window per channel;
// per-c funnel read as one unaligned 8B access (-> ds_read2_b32).
// PTpad[b][1+t] bit c = s[c][t-e_c]; PTpad[b][0]=0.
// ---------------------------------------------------------------------------
__global__ __launch_bounds__(256) void transpose_kernel(const uint32_t* __restrict__ sbits2,
                                                        const float4* __restrict__ efo,
                                                        uint32_t* __restrict__ PTpad) {
  __shared__ uint32_t rows[NH_][11];  // k=0..9 (+1 pad)
  int tid = threadIdx.x;
  int b = blockIdx.y;
  int t0blk = blockIdx.x * 256;
  int w0 = t0blk >> 5;
  const uint32_t* src = sbits2 + (size_t)b * 68 * NH_;
  for (int i = tid; i < NH_ * 10; i += 256) {
    int k = i >> 7, c = i & 127;
    rows[c][k] = src[(1 + w0 + k) * NH_ + c];  // slot 1+w0+k (guards at 0,1,66,67)
  }
  __syncthreads();

  int t = t0blk + tid;
  uint32_t wacc[4] = {0u, 0u, 0u, 0u};
#pragma unroll
  for (int c = 0; c < NH_; c++) {
    int e = __float_as_int(efo[c].x);           // uniform -> scalar load
    int bitpos = t - e;                          // >= t0blk-11
    int wi = (bitpos >> 5) - w0 + 1;             // in [0, 9]
    int sh = bitpos & 31;
    uint2 w2;
    __builtin_memcpy(&w2, &rows[c][wi], 8);      // unaligned 8B -> ds_read2_b32
    uint32_t bit = (uint32_t)(((((unsigned long long)w2.y << 32) | w2.x) >> sh)) & 1u;
    wacc[c >> 5] |= bit << (c & 31);
  }
  uint4* outp = (uint4*)PTpad + (size_t)b * (T_ + 1);
  outp[1 + t] = make_uint4(wacc[0], wacc[1], wacc[2], wacc[3]);
  if (t == 0) outp[0] = make_uint4(0u, 0u, 0u, 0u);
}

// ---------------------------------------------------------------------------
// gemm3 (vector): 5 outputs from pre-shifted PT rows.
// ---------------------------------------------------------------------------
__global__ __launch_bounds__(256) void gemm3_kernel(const uint32_t* __restrict__ PTpad,
                                                    const float* __restrict__ w3T,
                                                    float* __restrict__ z) {
  int tid = threadIdx.x;
  int t = blockIdx.x * 256 + tid;
  int b = blockIdx.y;
  const uint4* pt = (const uint4*)PTpad + (size_t)b * (T_ + 1);
  uint4 R0 = pt[t];
  uint4 R1 = pt[t + 1];
  uint32_t r0w[4] = {R0.x, R0.y, R0.z, R0.w};
  uint32_t r1w[4] = {R1.x, R1.y, R1.z, R1.w};

  float acc[NOUT_];
#pragma unroll
  for (int o = 0; o < NOUT_; o++) acc[o] = 0.f;

#pragma unroll
  for (int c = 0; c < NH_; c++) {
    const float* wc = w3T + (c << 3);
    float f = wc[5], omf = wc[6];
    float fb0 = (float)((r0w[c >> 5] >> (c & 31)) & 1u);
    float fb1 = (float)((r1w[c >> 5] >> (c & 31)) & 1u);
    float val = __fmaf_rn(omf, fb1, __fmul_rn(f, fb0));
#pragma unroll
    for (int o = 0; o < NOUT_; o++) acc[o] = __fmaf_rn(wc[o], val, acc[o]);
  }

#pragma unroll
  for (int o = 0; o < NOUT_; o++)
    z[((size_t)b * NOUT_ + o) * T_ + t] = acc[o];
}

// ---------------------------------------------------------------------------
// Chunked layer-3 scan: thread per (chunk, b, o); 96-step warmup; f32 SHIFTED
// output (out[t]=s[t-1]) via float4 stores; count excludes t=T-1.
// ---------------------------------------------------------------------------
__global__ __launch_bounds__(256) void scan3_kernel(const float* __restrict__ z3,
                                                    float* __restrict__ out,
                                                    float* __restrict__ cnt) {
  int id = blockIdx.x * 256 + threadIdx.x;
  int row = id % (B_ * NOUT_);
  int ci = id / (B_ * NOUT_);
  int tstart = ci * CHT_;
  int t0 = (ci == 0) ? 0 : tstart - WARM_;
  const float4* zp4 = (const float4*)(z3 + (size_t)row * T_);

  float u = 0.f, v = 0.f, carry = 0.f;
  int cnt_i = 0;
  for (int gg = t0 / 16; gg < tstart / 16; gg++) {
#pragma unroll
    for (int q = 0; q < 4; q++) {
      float4 cv = zp4[gg * 4 + q];
      float zv[4] = {cv.x, cv.y, cv.z, cv.w};
#pragma unroll
      for (int j = 0; j < 4; j++) {
        u = addrn(mulrn(ALPHA_I_, u), zv[j]);
        v = addrn(mulrn(ALPHA_V_, v), u);
        bool s = (v >= THETA_);
        v = s ? 0.f : v;
        carry = s ? 1.f : 0.f;
      }
    }
  }
  float4* op4 = (float4*)(out + (size_t)row * T_ + tstart);
  for (int gg = 0; gg < CHT_ / 16; gg++) {
    float sarr[16];
#pragma unroll
    for (int q = 0; q < 4; q++) {
      float4 cv = zp4[(tstart / 16 + gg) * 4 + q];
      float zv[4] = {cv.x, cv.y, cv.z, cv.w};
#pragma unroll
      for (int j = 0; j < 4; j++) {
        u = addrn(mulrn(ALPHA_I_, u), zv[j]);
        v = addrn(mulrn(ALPHA_V_, v), u);
        bool s = (v >= THETA_);
        v = s ? 0.f : v;
        sarr[q * 4 + j] = s ? 1.f : 0.f;
      }
    }
#pragma unroll
    for (int k = 0; k < 16; k++) {
      int t = tstart + gg * 16 + k;
      if (t < T_ - 1) cnt_i += (sarr[k] != 0.f) ? 1 : 0;
    }
    op4[gg * 4 + 0] = make_float4(carry, sarr[0], sarr[1], sarr[2]);
    op4[gg * 4 + 1] = make_float4(sarr[3], sarr[4], sarr[5], sarr[6]);
    op4[gg * 4 + 2] = make_float4(sarr[7], sarr[8], sarr[9], sarr[10]);
    op4[gg * 4 + 3] = make_float4(sarr[11], sarr[12], sarr[13], sarr[14]);
    carry = sarr[15];
  }
  float c = (float)cnt_i;
  for (int off = 32; off; off >>= 1) c += __shfl_down(c, off, 64);
  if ((threadIdx.x & 63) == 0) atomicAdd(cnt, c);
}

// ---------------------------------------------------------------------------
extern "C" void kernel_launch(void* const* d_in, const int* in_sizes, int n_in,
                              void* d_out, int out_size, void* d_ws, size_t ws_size,
                              hipStream_t stream) {
  (void)in_sizes; (void)n_in; (void)out_size; (void)ws_size;
  const float* spike  = (const float*)d_in[0];
  const float* fc1_v  = (const float*)d_in[1];
  const float* fc1_g  = (const float*)d_in[2];
  const float* fc2_v  = (const float*)d_in[3];
  const float* fc2_g  = (const float*)d_in[4];
  const float* fc3_v  = (const float*)d_in[5];
  const float* fc3_g  = (const float*)d_in[6];
  const float* delay1 = (const float*)d_in[7];
  const float* delay2 = (const float*)d_in[8];
  float* out = (float*)d_out;

  float* ws = (float*)d_ws;
  float* w3T       = ws;                         // 1024 f
  float4* efo1     = (float4*)(ws + 1024);       // 512 f
  float4* efo2     = (float4*)(ws + 1536);       // 512 f
  uint16_t* w1swz  = (uint16_t*)(ws + 2048);     // 2048 u16 = 1024 f
  uint16_t* wswz   = (uint16_t*)(ws + 3072);     // 32768 u16 = 16384 f
  uint16_t* Xb     = (uint16_t*)(ws + 19456);    // B*T u16 = 131072 f
  uint32_t* sbits2 = (uint32_t*)(ws + 150528);   // B*68*128 u32
  uint32_t* PTpad  = (uint32_t*)(ws + 1264640);  // B*(T+1)*4 u32, 16B-aligned
  float* z3        = ws + 2313728;               // B*5*T f32
  float* counts = out + (size_t)B_ * NOUT_ * T_;

  prep_kernel<<<1, 1024, 0, stream>>>(fc1_v, fc1_g, fc2_v, fc2_g, fc3_v, fc3_g,
                                      delay1, delay2, w1swz, wswz, w3T, efo1, efo2, counts);

  pack_kernel<<<dim3(B_ * T_ / 64 / 4), 256, 0, stream>>>(spike, Xb);

  fused_layer1<<<dim3(NCHUNK_, B_), 128, 0, stream>>>(Xb, w1swz, sbits2, counts + 0);
  transpose_kernel<<<dim3(T_ / 256, B_), 256, 0, stream>>>(sbits2, efo1, PTpad);

  fused_layer2<<<dim3(NCHUNK_, B_), 128, 0, stream>>>(PTpad, wswz, sbits2, counts + 1);
  transpose_kernel<<<dim3(T_ / 256, B_), 256, 0, stream>>>(sbits2, efo2, PTpad);

  gemm3_kernel<<<dim3(T_ / 256, B_), 256, 0, stream>>>(PTpad, w3T, z3);
  scan3_kernel<<<dim3(NCHUNK_ * B_ * NOUT_ / 256), 256, 0, stream>>>(z3, out, counts + 2);
}